// Round 8
// baseline (306.608 us; speedup 1.0000x reference)
//
#include <hip/hip_runtime.h>
#include <math.h>
#include <stdint.h>

#define CNUM 19
#define NB 4
#define HW 589824            // 768*768
#define NPIX 2359296         // NB*HW

// k_fused: 512 threads = 8 waves; each wave owns 256 px (64 lanes x 4).
// Per wave: 8-deep channel ring in LDS filled by global_load_lds (1 KB/slot),
// counted s_waitcnt vmcnt(N) -- 7 channel-loads continuously in flight per
// wave, no barriers in the main loop (wave-private LDS regions).
#define TPB 512
#define WAVES 8
#define WPX 256              // px per wave
#define TILE (WAVES * WPX)   // 2048 px per block; HW % TILE == 0
#define DEPTH 8              // ring slots

typedef __attribute__((address_space(3))) void lds_void;
typedef const __attribute__((address_space(1))) void glb_void;

// ---------------------------------------------------------------- workspace
struct ImgAcc2 {
  double sS[CNUM];          // sum of -log p over valid px of class c
  double sA[CNUM];          // same, att-masked (edge > 0.8)
  unsigned int cS[CNUM];    // count (== histogram bin)
  unsigned int cA[CNUM];    // att count (== att histogram bin)
  unsigned int pad[2];
};

struct Ws {
  ImgAcc2 img[NB];
  double bce_p, bce_n;      // sum of bce over pos / neg px (batch-global)
  unsigned int np, nn;      // pos / neg counts (batch-global)
};

// ---------------------------------------------------------------- init
__global__ void k_init(Ws* ws) {
  unsigned int* p = (unsigned int*)ws;
  const int nw = (int)(sizeof(Ws) / 4);
  for (int i = threadIdx.x; i < nw; i += blockDim.x) p[i] = 0u;
}

// ---------------------------------------------------------------- fused main
__global__ __launch_bounds__(TPB) void k_fused(const float* __restrict__ segin,
                                               const float* __restrict__ edgein,
                                               const int* __restrict__ segmask,
                                               const int* __restrict__ edgemask,
                                               Ws* __restrict__ wsw) {
  const int n = blockIdx.y;
  const int t = threadIdx.x;
  const int tile0 = blockIdx.x * TILE;
  const int wv = t >> 6;
  const int lane = t & 63;

  // per-wave channel ring: 8 slots x 256 f32 (1 KB) each = 64 KB
  __shared__ float ring[WAVES][DEPTH][256];
  // per-wave accumulation rows (+1 pad col)
  __shared__ float lsS[WAVES][CNUM + 1], lsA[WAVES][CNUM + 1];
  __shared__ unsigned int lcS[WAVES][CNUM + 1], lcA[WAVES][CNUM + 1];
  __shared__ float sbp, sbn;
  __shared__ unsigned int snp, snn;

  if (t < WAVES * (CNUM + 1)) {
    ((float*)lsS)[t] = 0.f; ((float*)lsA)[t] = 0.f;
    ((unsigned int*)lcS)[t] = 0u; ((unsigned int*)lcA)[t] = 0u;
  }
  if (t == WAVES * (CNUM + 1)) { sbp = 0.f; sbn = 0.f; snp = 0u; snn = 0u; }
  __syncthreads();

  // this thread's 4 pixels
  const int pxg = n * HW + tile0 + wv * WPX + lane * 4;

  // prologue: masks + edge (consumed now -> their vmcnt drains here)
  int4   tm = *reinterpret_cast<const int4*>(segmask + pxg);
  float4 ev = *reinterpret_cast<const float4*>(edgein + pxg);
  int4   em = *reinterpret_cast<const int4*>(edgemask + pxg);

  int tcv[4];
  unsigned int inbits = 0u;
  float ea[4] = {ev.x, ev.y, ev.z, ev.w};
  int   ma[4] = {em.x, em.y, em.z, em.w};
  {
    int ta[4] = {tm.x, tm.y, tm.z, tm.w};
    #pragma unroll
    for (int j = 0; j < 4; ++j) {
      tcv[j] = min(max(ta[j], 0), CNUM - 1);
      inbits |= (((unsigned)ta[j]) < (unsigned)CNUM) ? (1u << j) : 0u;
    }
  }

  // hard drain: from here on, the ONLY outstanding vmem ops are our stages,
  // so the counted vmcnt(N) discipline below is exact.
  asm volatile("s_waitcnt vmcnt(0)" ::: "memory");
  __builtin_amdgcn_sched_barrier(0);

  // per-lane global source for channel c = srcc + c*HW (16 B per lane)
  const float* srcc = segin + (size_t)n * CNUM * HW + tile0 + wv * WPX + lane * 4;

#define STAGE(c, s)                                                         \
  __builtin_amdgcn_global_load_lds(                                         \
      (glb_void*)(srcc + (size_t)(c) * HW),                                 \
      (lds_void*)(&ring[wv][(s)][0]), 16, 0, 0)

  // fill the ring: channels 0..6 in flight
  STAGE(0, 0); STAGE(1, 1); STAGE(2, 2); STAGE(3, 3);
  STAGE(4, 4); STAGE(5, 5); STAGE(6, 6);

  float sacc[4] = {0.f, 0.f, 0.f, 0.f};
  float xt[4]   = {0.f, 0.f, 0.f, 0.f};

  // STEP(c, K): pin order (nothing crosses above previous step's slot-read),
  // issue the prefetch for channel c+7 (overwrites slot read at step c-1,
  // already consumed), wait until channel c's DMA has landed (K outstanding
  // remain), then ds_read the slot and accumulate.
#define STEP(c, K)                                                          \
  do {                                                                      \
    __builtin_amdgcn_sched_barrier(0);                                      \
    if ((c) + DEPTH - 1 < CNUM)                                             \
      STAGE((c) + DEPTH - 1, ((c) + DEPTH - 1) & (DEPTH - 1));              \
    asm volatile("s_waitcnt vmcnt(" #K ")" ::: "memory");                   \
    __builtin_amdgcn_sched_barrier(0);                                      \
    {                                                                       \
      float4 v4 = *reinterpret_cast<const float4*>(                         \
          &ring[wv][(c) & (DEPTH - 1)][lane * 4]);                          \
      sacc[0] += __expf(v4.x); xt[0] = (tcv[0] == (c)) ? v4.x : xt[0];      \
      sacc[1] += __expf(v4.y); xt[1] = (tcv[1] == (c)) ? v4.y : xt[1];      \
      sacc[2] += __expf(v4.z); xt[2] = (tcv[2] == (c)) ? v4.z : xt[2];      \
      sacc[3] += __expf(v4.w); xt[3] = (tcv[3] == (c)) ? v4.w : xt[3];      \
    }                                                                       \
  } while (0)

  STEP(0, 7);  STEP(1, 7);  STEP(2, 7);  STEP(3, 7);
  STEP(4, 7);  STEP(5, 7);  STEP(6, 7);  STEP(7, 7);
  STEP(8, 7);  STEP(9, 7);  STEP(10, 7); STEP(11, 7);
  STEP(12, 6); STEP(13, 5); STEP(14, 4); STEP(15, 3);
  STEP(16, 2); STEP(17, 1); STEP(18, 0);

#undef STEP
#undef STAGE

  // epilogue: per-class LDS accumulation + BCE
  float bpos = 0.f, bneg = 0.f;
  int cntp = 0, cntn = 0;
  #pragma unroll
  for (int j = 0; j < 4; ++j) {
    float nlp = __logf(sacc[j]) - xt[j];     // -log p
    if ((inbits >> j) & 1u) {
      atomicAdd(&lsS[wv][tcv[j]], nlp);
      atomicAdd(&lcS[wv][tcv[j]], 1u);
      if (ea[j] > 0.8f) {
        atomicAdd(&lsA[wv][tcv[j]], nlp);
        atomicAdd(&lcA[wv][tcv[j]], 1u);
      }
    }
    float e = ea[j];
    int m = ma[j];
    float bce = fmaxf(e, 0.f) - e * (float)m + log1pf(__expf(-fabsf(e)));
    if (m == 1) { bpos += bce; ++cntp; }
    else if (m == 0) { bneg += bce; ++cntn; }
  }

  #pragma unroll
  for (int off = 32; off > 0; off >>= 1) {
    bpos += __shfl_down(bpos, off);
    bneg += __shfl_down(bneg, off);
    cntp += __shfl_down(cntp, off);
    cntn += __shfl_down(cntn, off);
  }
  if (lane == 0) {
    atomicAdd(&sbp, bpos);
    atomicAdd(&sbn, bneg);
    atomicAdd(&snp, (unsigned int)cntp);
    atomicAdd(&snn, (unsigned int)cntn);
  }
  __syncthreads();

  // flush: sum the 8 wave rows, one global atomic per accumulator
  if (t < CNUM) {
    float v = 0.f;
    #pragma unroll
    for (int w = 0; w < WAVES; ++w) v += lsS[w][t];
    atomicAdd(&wsw->img[n].sS[t], (double)v);
  } else if (t >= 32 && t < 32 + CNUM) {
    int c = t - 32;
    float v = 0.f;
    #pragma unroll
    for (int w = 0; w < WAVES; ++w) v += lsA[w][c];
    atomicAdd(&wsw->img[n].sA[c], (double)v);
  } else if (t >= 64 && t < 64 + CNUM) {
    int c = t - 64;
    unsigned int v = 0u;
    #pragma unroll
    for (int w = 0; w < WAVES; ++w) v += lcS[w][c];
    if (v) atomicAdd(&wsw->img[n].cS[c], v);
  } else if (t >= 96 && t < 96 + CNUM) {
    int c = t - 96;
    unsigned int v = 0u;
    #pragma unroll
    for (int w = 0; w < WAVES; ++w) v += lcA[w][c];
    if (v) atomicAdd(&wsw->img[n].cA[c], v);
  } else if (t == 128) {
    atomicAdd(&wsw->bce_p, (double)sbp);
  } else if (t == 129) {
    atomicAdd(&wsw->bce_n, (double)sbn);
  } else if (t == 130) {
    atomicAdd(&wsw->np, snp);
  } else if (t == 131) {
    atomicAdd(&wsw->nn, snn);
  }
}

// ---------------------------------------------------------------- finalize
__global__ void k_final(const Ws* __restrict__ ws, float* __restrict__ out) {
  if (threadIdx.x == 0 && blockIdx.x == 0) {
    double segl = 0.0, attl = 0.0;
    for (int i = 0; i < NB; ++i) {
      const ImgAcc2* a = &ws->img[i];
      double totS = 0.0, totA = 0.0;
      for (int c = 0; c < CNUM; ++c) { totS += (double)a->cS[c]; totA += (double)a->cA[c]; }
      double numS = 0.0, denS = 0.0, numA = 0.0, denA = 0.0;
      for (int c = 0; c < CNUM; ++c) {
        double bS = (double)a->cS[c];
        double wS = (bS != 0.0 ? (1.0 - bS / totS) : 0.0) + 1.0;
        numS += wS * a->sS[c];
        denS += wS * bS;
        double bA = (double)a->cA[c];
        double wA = (bA != 0.0 ? (1.0 - bA / totA) : 0.0) + 1.0;
        numA += wA * a->sA[c];
        denA += wA * bA;
      }
      segl += numS / denS;
      attl += numA / denA;
    }
    double s = (double)ws->np + (double)ws->nn;
    double wpos = (double)ws->nn / s;
    double wneg = (double)ws->np / s;
    double edgel = (wpos * ws->bce_p + wneg * ws->bce_n) / (double)NPIX;
    out[0] = (float)(segl + 0.3 * edgel + 0.1 * attl);
  }
}

// ---------------------------------------------------------------- launch
extern "C" void kernel_launch(void* const* d_in, const int* in_sizes, int n_in,
                              void* d_out, int out_size, void* d_ws, size_t ws_size,
                              hipStream_t stream) {
  const float* segin   = (const float*)d_in[0];
  const float* edgein  = (const float*)d_in[1];
  const int*   segmask = (const int*)d_in[2];
  const int*   edgemask= (const int*)d_in[3];
  Ws* ws = (Ws*)d_ws;
  float* out = (float*)d_out;

  hipLaunchKernelGGL(k_init,  dim3(1),             dim3(256), 0, stream, ws);
  hipLaunchKernelGGL(k_fused, dim3(HW / TILE, NB), dim3(TPB), 0, stream, segin, edgein, segmask, edgemask, ws);
  hipLaunchKernelGGL(k_final, dim3(1),             dim3(1),   0, stream, ws, out);
}